// Round 5
// baseline (625.886 us; speedup 1.0000x reference)
//
#include <hip/hip_runtime.h>

// RadarRnn1: 4-layer tanh RNN (B=512,S=1024,IN=64,H=32) + per-step FC + softmax over S.
// R13: R9/R10/R12 measurements isolate the remaining cost as structural to the
// barrier schedule: ~280cy/iter rendezvous+lgkmcnt(0) drain, and the own-h LDS
// roundtrip serialized inside each barrier window. Total VALU issue is only
// ~31% of the kernel wall => ~3x headroom from overlap that the barrier forbids.
// Fix: BARRIER-FREE producer/consumer pipeline.
//   - wave l free-runs its own t = 0..1023 loop; cross-layer handoff via
//     per-layer LDS rings (depth 32, 64B/step packed f16x2) + progress/claim
//     counters polled once per 8-step window (__hip_atomic acquire/release,
//     WORKGROUP scope). DS ops are in-order per wave => producer's data
//     writes commit before its counter write; consumer's counter read
//     precedes its data reads. Claim-before-wait ordering => deadlock-free;
//     bands: consumer needs prod >= T+9, producer needs claim >= T-24.
//   - own-h carry: write ring slot then read it back (same-wave in-order RAW);
//     no barrier ever forces a full drain, so u0/global stores/input
//     prefetches stay in flight.
//   - FC on wave 0, LAG=48 behind its layer-0 step, reading wave3's f32 h3
//     ring (depth 64): identical f32 DPP-cascade numerics as R10/R12.
// Arithmetic identical to R12 (same fdot2/dpp/tanh/FC ops) -> same absmax.
// u0_kernel / softmax_kernel unchanged.

#define BB 512
#define SS 1024
#define INF 64
#define HH 32
#define LL 4

typedef __fp16 v2h __attribute__((ext_vector_type(2)));

__device__ __forceinline__ v2h bch(unsigned u) { return __builtin_bit_cast(v2h, u); }
__device__ __forceinline__ unsigned bcu(v2h h) { return __builtin_bit_cast(unsigned, h); }

template <int CTRL>
__device__ __forceinline__ float dpp_add(float v) {
  int y = __builtin_amdgcn_update_dpp(0, __float_as_int(v), CTRL, 0xF, 0xF, true);
  return v + __int_as_float(y);
}
template <int CTRL>
__device__ __forceinline__ float dpp_mov(float v) {
  int y = __builtin_amdgcn_update_dpp(0, __float_as_int(v), CTRL, 0xF, 0xF, true);
  return __int_as_float(y);
}

// tanh(a) = 1 - 2/(e^{2a}+1); e^{2a} = 2^(a * 2/ln2). v_exp + v_rcp + fma.
__device__ __forceinline__ float tanh_fast(float a) {
  const float e = __builtin_amdgcn_exp2f(a * 2.885390081777927f);
  const float r = __builtin_amdgcn_rcpf(e + 1.0f);
  return __builtin_fmaf(-2.0f, r, 1.0f);
}

// 16-half dot (ks-half): 8 fdot2 in 2 chains of depth 4.
__device__ __forceinline__ float dot16p(const v2h* w, const v2h* v) {
  float a = 0.f, c = 0.f;
#pragma unroll
  for (int j = 0; j < 4; ++j) {
    a = __builtin_amdgcn_fdot2(w[2 * j + 0], v[2 * j + 0], a, false);
    c = __builtin_amdgcn_fdot2(w[2 * j + 1], v[2 * j + 1], c, false);
  }
  return a + c;
}

// LDS flow-control primitives (workgroup scope). Acquire/release give both HW
// and COMPILER ordering vs the surrounding plain ds ops.
__device__ __forceinline__ void wait_ge(const int* p, int v) {
  while (__hip_atomic_load(p, __ATOMIC_ACQUIRE, __HIP_MEMORY_SCOPE_WORKGROUP) < v)
    __builtin_amdgcn_s_sleep(2);
}
__device__ __forceinline__ void sig_store(int* p, int v) {
  __hip_atomic_store(p, v, __ATOMIC_RELEASE, __HIP_MEMORY_SCOPE_WORKGROUP);
}

// ---------------- u0 = x @ W_ih0^T + (b_ih0 + b_hh0) ----------------
__global__ __launch_bounds__(256) void u0_kernel(
    const float* __restrict__ x, const float* __restrict__ W_ih0,
    const float* __restrict__ b_ih, const float* __restrict__ b_hh,
    float* __restrict__ u0) {
  __shared__ float Wl[HH * INF];  // [u][k]
  __shared__ float bl[HH];
  const int tid = threadIdx.x;
  {
    const float4* src = (const float4*)W_ih0;
    float4* dst = (float4*)Wl;
    dst[tid] = src[tid];
    dst[tid + 256] = src[tid + 256];
    if (tid < HH) bl[tid] = b_ih[tid] + b_hh[tid];
  }
  __syncthreads();

  const int row = blockIdx.x * 256 + tid;  // 2048 blocks x 256 rows
  const float4* xr = (const float4*)(x + (size_t)row * INF);
  float acc[HH];
#pragma unroll
  for (int u = 0; u < HH; ++u) acc[u] = bl[u];
#pragma unroll 4
  for (int kc = 0; kc < 16; ++kc) {
    const float4 xv = xr[kc];
#pragma unroll
    for (int u = 0; u < HH; ++u) {
      const float4 wv = ((const float4*)Wl)[u * 16 + kc];  // wave-broadcast
      acc[u] += wv.x * xv.x + wv.y * xv.y + wv.z * xv.z + wv.w * xv.w;
    }
  }
  float4* op = (float4*)(u0 + (size_t)row * HH);
#pragma unroll
  for (int j = 0; j < 8; ++j)
    op[j] = make_float4(acc[4 * j], acc[4 * j + 1], acc[4 * j + 2], acc[4 * j + 3]);
}

// ---------------- recurrent kernel: 4 free-running waves, LDS rings ----------------
__global__ __launch_bounds__(256, 2) void rnn_kernel(
    const float* __restrict__ u0g_all, const float* __restrict__ h_state,
    const float* __restrict__ W_ih_rest, const float* __restrict__ W_hh,
    const float* __restrict__ b_ih, const float* __restrict__ b_hh,
    const float* __restrict__ fc_w, const float* __restrict__ fc_b,
    float* __restrict__ out) {
  __shared__ __align__(16) int ring[LL][32][16];  // [layer][t&31][pair] f16x2, 64B/step
  __shared__ float h3ring[64][HH];                // wave3's f32 hv for FC, depth 64
  __shared__ float lbuf[64];                      // logit staging (wave 0)
  __shared__ int prog[LL];                        // producer: last completed t
  __shared__ int rcl[LL];                         // consumer claim: min future read t

  const int tid  = threadIdx.x;
  const int wid  = tid >> 6;   // wave id == layer id
  const int lane = tid & 63;
  const int b    = blockIdx.x; // one batch element per block
  const int ks   = lane & 1;   // k-split half
  const int h    = lane >> 1;  // output unit 0..31

  if (tid < LL) { prog[tid] = -1; rcl[tid] = 0; }

  // weights: f16-packed h-matrices only (x-part of layer 0 lives in u0)
  v2h wih[8], whh[8];
  {
    const float2* ph = (const float2*)(W_hh + (size_t)(wid * HH + h) * HH + ks * 16);
#pragma unroll
    for (int j = 0; j < 8; ++j) whh[j] = __builtin_amdgcn_cvt_pkrtz(ph[j].x, ph[j].y);
  }
  float bias = 0.f;  // layer 0 bias folded into u0
  if (wid > 0) {
    const float2* pi =
        (const float2*)(W_ih_rest + (size_t)((wid - 1) * HH + h) * HH + ks * 16);
#pragma unroll
    for (int j = 0; j < 8; ++j) wih[j] = __builtin_amdgcn_cvt_pkrtz(pi[j].x, pi[j].y);
    bias = b_ih[wid * HH + h] + b_hh[wid * HH + h];
  }
  const float fcwh = fc_w[h] * 0.5f;  // both ks lanes hold hv -> 64-lane sum is 2x
  const float fcb  = fc_b[0];

  // own h(-1) straight into registers (packed ks-half)
  v2h sv[8];
  {
    const float2* hs = (const float2*)(h_state + (size_t)(wid * BB + b) * HH);
#pragma unroll
    for (int j = 0; j < 8; ++j)
      sv[j] = __builtin_amdgcn_cvt_pkrtz(hs[ks * 8 + j].x, hs[ks * 8 + j].y);
  }

  const float* ug = u0g_all + (size_t)b * SS * HH;
  float* const outrow = out + (size_t)b * SS;
  float* const hfin   = out + (size_t)BB * SS;

  auto ld8 = [&](const int* p, v2h* v) __attribute__((always_inline)) {
    const uint4* q = (const uint4*)p;
    uint4 A = q[0], B = q[1];
    v[0] = bch(A.x); v[1] = bch(A.y); v[2] = bch(A.z); v[3] = bch(A.w);
    v[4] = bch(B.x); v[5] = bch(B.y); v[6] = bch(B.z); v[7] = bch(B.w);
  };
  // pack own hv with neighbor-unit hv (quad_perm [2,3,2,3]) and store by 16 lanes
  auto store_h = [&](int l, int slot, float hv) __attribute__((always_inline)) {
    float partner = dpp_mov<0xEE>(hv);
    if ((lane & 3) == 0)
      ring[l][slot][lane >> 2] = (int)bcu(__builtin_amdgcn_cvt_pkrtz(hv, partner));
  };
  auto fcred = [&](float v) __attribute__((always_inline)) {
    v = dpp_add<0x111>(v);  // row_shr:1
    v = dpp_add<0x112>(v);  // row_shr:2
    v = dpp_add<0x114>(v);  // row_shr:4
    v = dpp_add<0x118>(v);  // row_shr:8
    v = dpp_add<0x142>(v);  // row_bcast:15
    v = dpp_add<0x143>(v);  // row_bcast:31
    return v;               // lane 63 holds the 64-lane sum
  };

  __syncthreads();  // counters initialized; the ONLY barrier in the kernel

  if (wid == 0) {
    // wave 0: layer 0 (input = u0 from global) + FC at LAG=48 behind.
    float ur[8];
#pragma unroll
    for (int i = 0; i < 8; ++i) ur[i] = ug[i * HH + h];
    float fcq[4];
    for (int W = 0; W < 134; ++W) {
      const int T = W * 8;
      const bool lw = (T < SS);
      const int Tf = T - 48;
      const bool fw = (Tf >= 0);  // Tf < 1024 by loop bound
      if (lw) wait_ge(&rcl[0], T - 24);  // ring0 space (w1's claim)
      if (fw) wait_ge(&prog[3], (Tf + 9 < SS) ? Tf + 9 : SS - 1);
      if (W == 6) { fcq[0] = h3ring[0][h]; fcq[1] = h3ring[1][h]; }
#pragma unroll
      for (int j = 0; j < 8; ++j) {
        const int t = T + j;
        if (lw) {  // wave-uniform
          float acc = dot16p(whh, sv);
          acc = dpp_add<0xB1>(acc) + ur[j];  // u0 holds x-part + full bias0
          const float hv = tanh_fast(acc);
          store_h(0, t & 31, hv);
          ld8(&ring[0][t & 31][ks * 8], sv);  // own carry (in-wave in-order RAW)
          if (t == SS - 1 && ks == 0) hfin[(0 * BB + b) * HH + h] = hv;
          int tl = t + 8; tl = (tl < SS) ? tl : (SS - 1);
          ur[j] = ug[tl * HH + h];
        }
        if (fw) {  // FC for timestep tf (exact f32 cascade, as R10/R12)
          const int tf = Tf + j;
          fcq[(j + 2) & 3] = h3ring[(tf + 2) & 63][h];  // prefetch 2 ahead
          float v = fcred(fcq[j & 3] * fcwh);
          if (lane == 63) lbuf[tf & 63] = v + fcb;
          if ((tf & 63) == 63) {  // coalesced flush of 64 logits
            float lv = lbuf[lane];
            outrow[tf - 63 + lane] = lv;
          }
        }
      }
      if (lw && lane == 0) sig_store(&prog[0], T + 7);
    }
  } else {
    // waves 1..3: layer wid, input from ring[wid-1], output to ring[wid].
    v2h vi[4][8];  // input slots, depth-4 rotation, prefetch distance 2
    for (int W = 0; W < 128; ++W) {
      const int T = W * 8;
      if (lane == 0) sig_store(&rcl[wid - 1], T);  // claim BEFORE waits
      wait_ge(&prog[wid - 1], (T + 9 < SS) ? T + 9 : SS - 1);
      if (wid < 3) wait_ge(&rcl[wid], T - 24);     // own-ring space guard
      if (W == 0) {  // initial preload of slots 0,1
        ld8(&ring[wid - 1][0][ks * 8], vi[0]);
        ld8(&ring[wid - 1][1][ks * 8], vi[1]);
      }
#pragma unroll
      for (int j = 0; j < 8; ++j) {
        const int t = T + j;
        ld8(&ring[wid - 1][(t + 2) & 31][ks * 8], vi[(j + 2) & 3]);  // prefetch t+2
        float acc = dot16p(wih, vi[j & 3]) + dot16p(whh, sv);
        acc = dpp_add<0xB1>(acc) + bias;
        const float hv = tanh_fast(acc);
        store_h(wid, t & 31, hv);
        if (wid == 3 && ks == 0) h3ring[t & 63][h] = hv;  // f32 handoff to FC
        ld8(&ring[wid][t & 31][ks * 8], sv);  // own carry (in-order RAW)
        if (t == SS - 1 && ks == 0) hfin[(wid * BB + b) * HH + h] = hv;
      }
      if (lane == 0) sig_store(&prog[wid], T + 7);
    }
  }
}

__global__ __launch_bounds__(256) void softmax_kernel(float* __restrict__ out) {
  __shared__ float red[8];
  const int row = blockIdx.x;
  float* p = out + (size_t)row * SS;
  const int tid = threadIdx.x;
  float4 v = ((const float4*)p)[tid];  // 256 threads x 4 = 1024 logits
  float m = fmaxf(fmaxf(v.x, v.y), fmaxf(v.z, v.w));
#pragma unroll
  for (int d = 32; d >= 1; d >>= 1) m = fmaxf(m, __shfl_xor(m, d));
  if ((tid & 63) == 0) red[tid >> 6] = m;
  __syncthreads();
  m = fmaxf(fmaxf(red[0], red[1]), fmaxf(red[2], red[3]));
  const float e0 = __expf(v.x - m), e1 = __expf(v.y - m);
  const float e2 = __expf(v.z - m), e3 = __expf(v.w - m);
  float s = (e0 + e1) + (e2 + e3);
#pragma unroll
  for (int d = 32; d >= 1; d >>= 1) s += __shfl_xor(s, d);
  if ((tid & 63) == 0) red[4 + (tid >> 6)] = s;
  __syncthreads();
  s = (red[4] + red[5]) + (red[6] + red[7]);
  const float inv = 1.0f / s;
  float4 o;
  o.x = e0 * inv; o.y = e1 * inv; o.z = e2 * inv; o.w = e3 * inv;
  ((float4*)p)[tid] = o;
}

extern "C" void kernel_launch(void* const* d_in, const int* in_sizes, int n_in,
                              void* d_out, int out_size, void* d_ws, size_t ws_size,
                              hipStream_t stream) {
  const float* x         = (const float*)d_in[0];
  const float* h_state   = (const float*)d_in[1];
  const float* W_ih0     = (const float*)d_in[2];
  const float* W_ih_rest = (const float*)d_in[3];
  const float* W_hh      = (const float*)d_in[4];
  const float* b_ih      = (const float*)d_in[5];
  const float* b_hh      = (const float*)d_in[6];
  const float* fc_w      = (const float*)d_in[7];
  const float* fc_b      = (const float*)d_in[8];
  float* out = (float*)d_out;
  float* u0  = (float*)d_ws;  // [B,S,32] fp32 = 67 MB scratch

  hipLaunchKernelGGL(u0_kernel, dim3((BB * SS) / 256), dim3(256), 0, stream,
                     x, W_ih0, b_ih, b_hh, u0);
  hipLaunchKernelGGL(rnn_kernel, dim3(BB), dim3(256), 0, stream,
                     u0, h_state, W_ih_rest, W_hh, b_ih, b_hh, fc_w, fc_b, out);
  hipLaunchKernelGGL(softmax_kernel, dim3(BB), dim3(256), 0, stream, out);
}

// Round 6
// 618.803 us; speedup vs baseline: 1.0114x; 1.0114x over previous
//
#include <hip/hip_runtime.h>

// RadarRnn1: 4-layer tanh RNN (B=512,S=1024,IN=64,H=32) + per-step FC + softmax over S.
// R14: revert R13 (HIP atomic release emits vmcnt(0)+lgkmcnt(0) drains + ~120cy
// polling roundtrips; 245->423us). Base = R12 (245us). Two independent changes:
// (1) rnn: own-h carry via ds_bpermute instead of ds_write->ds_read roundtrip.
//     The packed h-words live in registers of lanes 4m; the carry is a pure
//     cross-lane gather: dest lane (h,ks) needs word 8ks+w from lane 32ks+4w
//     -> 8x ds_bpermute (idx = 128*ks + 16*w), ONE LDS traversal instead of
//     two, no write dependency. store_h stays for the consumer wave (off the
//     critical path); wave 3 has no ring consumer -> drops stores entirely.
//     Bit-identical arithmetic.
// (2) u0: LDS staging deleted; W/bias read directly with wave-uniform indices
//     (fully unrolled, constant offsets) -> compiler emits s_load (K$-cached,
//     W=8KB fits). Old version was LDS-issue-bound (512 uniform ds_read_b128
//     per wave = 16B/instr broadcast). Identical f32 expression order.
// softmax_kernel unchanged.

#define BB 512
#define SS 1024
#define INF 64
#define HH 32
#define LL 4

typedef __fp16 v2h __attribute__((ext_vector_type(2)));

__device__ __forceinline__ v2h bch(unsigned u) { return __builtin_bit_cast(v2h, u); }
__device__ __forceinline__ unsigned bcu(v2h h) { return __builtin_bit_cast(unsigned, h); }

template <int CTRL>
__device__ __forceinline__ float dpp_add(float v) {
  int y = __builtin_amdgcn_update_dpp(0, __float_as_int(v), CTRL, 0xF, 0xF, true);
  return v + __int_as_float(y);
}
template <int CTRL>
__device__ __forceinline__ float dpp_mov(float v) {
  int y = __builtin_amdgcn_update_dpp(0, __float_as_int(v), CTRL, 0xF, 0xF, true);
  return __int_as_float(y);
}

// tanh(a) = 1 - 2/(e^{2a}+1); e^{2a} = 2^(a * 2/ln2). v_exp + v_rcp + fma.
__device__ __forceinline__ float tanh_fast(float a) {
  const float e = __builtin_amdgcn_exp2f(a * 2.885390081777927f);
  const float r = __builtin_amdgcn_rcpf(e + 1.0f);
  return __builtin_fmaf(-2.0f, r, 1.0f);
}

// 16-half dot (ks-half): 8 fdot2 in 2 chains of depth 4.
__device__ __forceinline__ float dot16p(const v2h* w, const v2h* v) {
  float a = 0.f, c = 0.f;
#pragma unroll
  for (int j = 0; j < 4; ++j) {
    a = __builtin_amdgcn_fdot2(w[2 * j + 0], v[2 * j + 0], a, false);
    c = __builtin_amdgcn_fdot2(w[2 * j + 1], v[2 * j + 1], c, false);
  }
  return a + c;
}

// lgkmcnt-only barrier: drains LDS ops (cross-wave handoff) but leaves global
// loads/stores in flight (u0 prefetch, hfin/logit stores).
#define BAR() asm volatile("s_waitcnt lgkmcnt(0)\n\ts_barrier" ::: "memory")

// ---------------- u0 = x @ W_ih0^T + (b_ih0 + b_hh0) ----------------
// Thread-per-row GEMV; W and bias read via wave-uniform (scalar) loads, K$-hot
// after the first wave. x loads per-lane (64B lines fully consumed over kc).
__global__ __launch_bounds__(256) void u0_kernel(
    const float* __restrict__ x, const float* __restrict__ W_ih0,
    const float* __restrict__ b_ih, const float* __restrict__ b_hh,
    float* __restrict__ u0) {
  const int tid = threadIdx.x;
  const int row = blockIdx.x * 256 + tid;  // 2048 blocks x 256 rows
  const float4* xr = (const float4*)(x + (size_t)row * INF);
  float acc[HH];
#pragma unroll
  for (int u = 0; u < HH; ++u) acc[u] = b_ih[u] + b_hh[u];  // uniform -> scalar
#pragma unroll 4
  for (int kc = 0; kc < 16; ++kc) {
    const float4 xv = xr[kc];
#pragma unroll
    for (int u = 0; u < HH; ++u) {
      const float4 wv = ((const float4*)W_ih0)[u * 16 + kc];  // uniform -> s_load
      acc[u] += wv.x * xv.x + wv.y * xv.y + wv.z * xv.z + wv.w * xv.w;
    }
  }
  float4* op = (float4*)(u0 + (size_t)row * HH);
#pragma unroll
  for (int j = 0; j < 8; ++j)
    op[j] = make_float4(acc[4 * j], acc[4 * j + 1], acc[4 * j + 2], acc[4 * j + 3]);
}

// ---------------- recurrent kernel: 4 waves (one per layer), skew-2 barriers,
// prefetched LDS inputs, bpermute own-h carry ----------------
__global__ __launch_bounds__(256, 2) void rnn_kernel(
    const float* __restrict__ u0g_all, const float* __restrict__ h_state,
    const float* __restrict__ W_ih_rest, const float* __restrict__ W_hh,
    const float* __restrict__ b_ih, const float* __restrict__ b_hh,
    const float* __restrict__ fc_w, const float* __restrict__ fc_b,
    float* __restrict__ out) {
  __shared__ int hb[LL][2][2][16];  // [layer][buf=n&1][slot=t&1][pair] f16x2
  __shared__ float h3f[2][2][32];   // [buf][slot][unit]: wave3's f32 hv for FC
  __shared__ float lbuf[64];        // logit staging (wave 0)

  const int tid  = threadIdx.x;
  const int wid  = tid >> 6;   // wave id == layer id
  const int lane = tid & 63;
  const int b    = blockIdx.x; // one batch element per block
  const int ks   = lane & 1;   // k-split half
  const int h    = lane >> 1;  // output unit 0..31
  const int bidx = 128 * ks;   // bpermute byte-index base (lane 32*ks+4w -> *4)

  // weights: f16-packed h-matrices only (x-part of layer 0 lives in u0)
  v2h wih[8], whh[8];
  {
    const float2* ph = (const float2*)(W_hh + (size_t)(wid * HH + h) * HH + ks * 16);
#pragma unroll
    for (int j = 0; j < 8; ++j) whh[j] = __builtin_amdgcn_cvt_pkrtz(ph[j].x, ph[j].y);
  }
  float bias = 0.f;  // layer 0 bias folded into u0
  if (wid > 0) {
    const float2* pi =
        (const float2*)(W_ih_rest + (size_t)((wid - 1) * HH + h) * HH + ks * 16);
#pragma unroll
    for (int j = 0; j < 8; ++j) wih[j] = __builtin_amdgcn_cvt_pkrtz(pi[j].x, pi[j].y);
    bias = b_ih[wid * HH + h] + b_hh[wid * HH + h];
  }
  const float fcwh = fc_w[h] * 0.5f;  // both ks lanes hold hv -> 64-lane sum is 2x
  const float fcb  = fc_b[0];

  // own h(-1) straight into registers (packed ks-half)
  v2h sv[8];
  {
    const float2* hs = (const float2*)(h_state + (size_t)(wid * BB + b) * HH);
#pragma unroll
    for (int j = 0; j < 8; ++j)
      sv[j] = __builtin_amdgcn_cvt_pkrtz(hs[ks * 8 + j].x, hs[ks * 8 + j].y);
  }

  const float* ug = u0g_all + (size_t)b * SS * HH;
  float ur[8];  // rotating u0 prefetch (wave 0): 2 values/iter, 4 iters ahead
  if (wid == 0) {
#pragma unroll
    for (int i = 0; i < 8; ++i) ur[i] = ug[i * HH + h];
  }
  float* const outrow = out + (size_t)b * SS;
  float* const hfin   = out + (size_t)BB * SS;

  auto ld8 = [&](const int* p, v2h* v) __attribute__((always_inline)) {
    const uint4* q = (const uint4*)p;
    uint4 A = q[0], B = q[1];
    v[0] = bch(A.x); v[1] = bch(A.y); v[2] = bch(A.z); v[3] = bch(A.w);
    v[4] = bch(B.x); v[5] = bch(B.y); v[6] = bch(B.z); v[7] = bch(B.w);
  };
  // pack own hv with neighbor-unit hv (quad_perm [2,3,2,3]); word m valid at lane 4m
  auto packpair = [&](float hv) __attribute__((always_inline)) {
    return bcu(__builtin_amdgcn_cvt_pkrtz(hv, dpp_mov<0xEE>(hv)));
  };
  auto store_pk = [&](int l, int buf, int slot, unsigned pk) __attribute__((always_inline)) {
    if ((lane & 3) == 0) hb[l][buf][slot][lane >> 2] = (int)pk;
  };
  // own-h carry: gather this wave's packed words from lanes 32ks+4w (1 LDS pass)
  auto carry8 = [&](unsigned pk, v2h* v) __attribute__((always_inline)) {
#pragma unroll
    for (int w = 0; w < 8; ++w)
      v[w] = bch((unsigned)__builtin_amdgcn_ds_bpermute(bidx + 16 * w, (int)pk));
  };
  auto fcred = [&](float v) __attribute__((always_inline)) {
    v = dpp_add<0x111>(v);  // row_shr:1
    v = dpp_add<0x112>(v);  // row_shr:2
    v = dpp_add<0x114>(v);  // row_shr:4
    v = dpp_add<0x118>(v);  // row_shr:8
    v = dpp_add<0x142>(v);  // row_bcast:15
    v = dpp_add<0x143>(v);  // row_bcast:31
    return v;               // lane 63 holds the 64-lane sum
  };

  // Schedule: wave l computes pair p = n - 2l (t = 2p, 2p+1) at iteration n.
  // hb write buffer = n&1. Consumer input (producer pair p, written at n-2,
  // buf (n-2)&1 = n&1) is ds_read-issued at iter n-1 into vi[n&1] and is in
  // registers at BAR(n). Own h flows through registers via ds_bpermute.
  v2h vi[2][2][8];  // [iter parity][slot][word] - indices compile-time (j&1)

  if (wid == 0) {
    for (int n0 = 0; n0 < 520; n0 += 4) {
#pragma unroll
      for (int j = 0; j < 4; ++j) {
        BAR();
        const int n = n0 + j;
        const int buf = j & 1;  // == n&1 (n0 % 4 == 0)
        float a0 = 0.f, a1 = 0.f;
        const bool fc_on = (n >= 7 && n <= 518);
        if (fc_on) {
          a0 = h3f[buf ^ 1][0][h];
          a1 = h3f[buf ^ 1][1][h];
        }
        if (n <= 511) {  // wave-uniform
          float acc0 = dot16p(whh, sv);
          acc0 = dpp_add<0xB1>(acc0) + ur[2 * j];  // u0 holds x-part + bias0
          const float hv0 = tanh_fast(acc0);
          const unsigned pk0 = packpair(hv0);
          store_pk(0, buf, 0, pk0);
          v2h sv0[8];
          carry8(pk0, sv0);                 // 1-pass cross-lane gather
          float acc1 = dot16p(whh, sv0);
          acc1 = dpp_add<0xB1>(acc1) + ur[2 * j + 1];
          const float hv1 = tanh_fast(acc1);
          const unsigned pk1 = packpair(hv1);
          store_pk(0, buf, 1, pk1);
          carry8(pk1, sv);                  // carry to next iter
          if (n == 511 && ks == 0) hfin[(0 * BB + b) * HH + h] = hv1;
          int ta = 2 * n + 8; ta = ta < SS ? ta : SS - 1;
          int tb = 2 * n + 9; tb = tb < SS ? tb : SS - 1;
          ur[2 * j]     = ug[ta * HH + h];  // global; survives BAR (lgkm-only)
          ur[2 * j + 1] = ug[tb * HH + h];
        }
        if (fc_on) {  // FC for t = 2n-14, 2n-13 (wave3 pair from iter n-1)
          const int tf = 2 * n - 13;
          float v0 = fcred(a0 * fcwh);
          float v1 = fcred(a1 * fcwh);
          if (lane == 63) {
            lbuf[(tf - 1) & 63] = v0 + fcb;
            lbuf[tf & 63]       = v1 + fcb;
          }
          if ((tf & 63) == 63) {  // coalesced flush of 64 logits
            float lv = lbuf[lane];
            outrow[tf - 63 + lane] = lv;
          }
        }
      }
    }
  } else if (wid < 3) {
    const int lo = 2 * wid, hi = 511 + 2 * wid;
    for (int n0 = 0; n0 < 520; n0 += 4) {
#pragma unroll
      for (int j = 0; j < 4; ++j) {
        BAR();
        const int n = n0 + j;
        const int buf = j & 1;  // == n&1
        // prefetch input for iter n+1 (producer pair p+1, written at n-1,
        // buf (n-1)&1 = buf^1) -> vi[buf^1]
        if (n >= lo - 1 && n <= hi - 1) {
          ld8(&hb[wid - 1][buf ^ 1][0][ks * 8], vi[buf ^ 1][0]);
          ld8(&hb[wid - 1][buf ^ 1][1][ks * 8], vi[buf ^ 1][1]);
        }
        if (n >= lo && n <= hi) {  // wave-uniform
          float acc0 = dot16p(wih, vi[buf][0]) + dot16p(whh, sv);
          acc0 = dpp_add<0xB1>(acc0) + bias;
          const float hv0 = tanh_fast(acc0);
          const unsigned pk0 = packpair(hv0);
          store_pk(wid, buf, 0, pk0);
          v2h sv0[8];
          carry8(pk0, sv0);
          float acc1 = dot16p(wih, vi[buf][1]);  // independent: overlaps gather
          acc1 += dot16p(whh, sv0);
          acc1 = dpp_add<0xB1>(acc1) + bias;
          const float hv1 = tanh_fast(acc1);
          const unsigned pk1 = packpair(hv1);
          store_pk(wid, buf, 1, pk1);
          carry8(pk1, sv);
          if (n == hi && ks == 0) hfin[(wid * BB + b) * HH + h] = hv1;
        }
      }
    }
  } else {  // wave 3: layer 3 + publish f32 hv for wave0's FC (no ring stores)
    for (int n0 = 0; n0 < 520; n0 += 4) {
#pragma unroll
      for (int j = 0; j < 4; ++j) {
        BAR();
        const int n = n0 + j;
        const int buf = j & 1;  // == n&1
        if (n >= 5 && n <= 516) {
          ld8(&hb[2][buf ^ 1][0][ks * 8], vi[buf ^ 1][0]);
          ld8(&hb[2][buf ^ 1][1][ks * 8], vi[buf ^ 1][1]);
        }
        if (n >= 6 && n <= 517) {  // wave-uniform
          float acc0 = dot16p(wih, vi[buf][0]) + dot16p(whh, sv);
          acc0 = dpp_add<0xB1>(acc0) + bias;
          const float hv0 = tanh_fast(acc0);
          const unsigned pk0 = packpair(hv0);
          if (ks == 0) h3f[buf][0][h] = hv0;  // exact f32 handoff to wave0
          v2h sv0[8];
          carry8(pk0, sv0);
          float acc1 = dot16p(wih, vi[buf][1]);
          acc1 += dot16p(whh, sv0);
          acc1 = dpp_add<0xB1>(acc1) + bias;
          const float hv1 = tanh_fast(acc1);
          const unsigned pk1 = packpair(hv1);
          if (ks == 0) h3f[buf][1][h] = hv1;
          carry8(pk1, sv);
          if (n == 517 && ks == 0) hfin[(3 * BB + b) * HH + h] = hv1;
        }
      }
    }
  }
}

__global__ __launch_bounds__(256) void softmax_kernel(float* __restrict__ out) {
  __shared__ float red[8];
  const int row = blockIdx.x;
  float* p = out + (size_t)row * SS;
  const int tid = threadIdx.x;
  float4 v = ((const float4*)p)[tid];  // 256 threads x 4 = 1024 logits
  float m = fmaxf(fmaxf(v.x, v.y), fmaxf(v.z, v.w));
#pragma unroll
  for (int d = 32; d >= 1; d >>= 1) m = fmaxf(m, __shfl_xor(m, d));
  if ((tid & 63) == 0) red[tid >> 6] = m;
  __syncthreads();
  m = fmaxf(fmaxf(red[0], red[1]), fmaxf(red[2], red[3]));
  const float e0 = __expf(v.x - m), e1 = __expf(v.y - m);
  const float e2 = __expf(v.z - m), e3 = __expf(v.w - m);
  float s = (e0 + e1) + (e2 + e3);
#pragma unroll
  for (int d = 32; d >= 1; d >>= 1) s += __shfl_xor(s, d);
  if ((tid & 63) == 0) red[4 + (tid >> 6)] = s;
  __syncthreads();
  s = (red[4] + red[5]) + (red[6] + red[7]);
  const float inv = 1.0f / s;
  float4 o;
  o.x = e0 * inv; o.y = e1 * inv; o.z = e2 * inv; o.w = e3 * inv;
  ((float4*)p)[tid] = o;
}

extern "C" void kernel_launch(void* const* d_in, const int* in_sizes, int n_in,
                              void* d_out, int out_size, void* d_ws, size_t ws_size,
                              hipStream_t stream) {
  const float* x         = (const float*)d_in[0];
  const float* h_state   = (const float*)d_in[1];
  const float* W_ih0     = (const float*)d_in[2];
  const float* W_ih_rest = (const float*)d_in[3];
  const float* W_hh      = (const float*)d_in[4];
  const float* b_ih      = (const float*)d_in[5];
  const float* b_hh      = (const float*)d_in[6];
  const float* fc_w      = (const float*)d_in[7];
  const float* fc_b      = (const float*)d_in[8];
  float* out = (float*)d_out;
  float* u0  = (float*)d_ws;  // [B,S,32] fp32 = 67 MB scratch

  hipLaunchKernelGGL(u0_kernel, dim3((BB * SS) / 256), dim3(256), 0, stream,
                     x, W_ih0, b_ih, b_hh, u0);
  hipLaunchKernelGGL(rnn_kernel, dim3(BB), dim3(256), 0, stream,
                     u0, h_state, W_ih_rest, W_hh, b_ih, b_hh, fc_w, fc_b, out);
  hipLaunchKernelGGL(softmax_kernel, dim3(BB), dim3(256), 0, stream, out);
}

// Round 7
// 439.462 us; speedup vs baseline: 1.4242x; 1.4081x over previous
//
#include <hip/hip_runtime.h>

// RadarRnn1: 4-layer tanh RNN (B=512,S=1024,IN=64,H=32) + per-step FC + softmax over S.
// R15: revert R14 (bpermute broadcast = 3.4e7 bank conflicts, +74us; u0 s_load
// theory wrong, +88us). Key re-derivation from measured wall times:
//   R9 = 1135cy/iter (1 tick), R10 = 1172cy/iter (2 ticks), R12 = 1130cy/iter.
// The second tick cost only ~37cy => iterations are dominated by a ~1100cy
// FIXED per-barrier cost (rendezvous + drain + wake), under which one ~280cy
// tick-chain (R8's barrier-free 284cy/layer-tick confirms) hides almost fully.
// Correct model: per-iter = max(~1100, k*280). Lever = k (ticks per barrier).
// SKEW-8: wave l computes ticks 8(n-l)..8(n-l)+7 at iteration n, consuming the
// producer's same-range block written at n-1 (buf parity n&1, same proven
// double-buffer + lgkmcnt-only barrier discipline as R10/R12). 132 barriers
// instead of 520. Own-h carry keeps the proven store_pk -> ld8 in-order DS
// round trip. FC on wave 0 at one-iteration lag, identical f32 cascade.
// u0_kernel / softmax_kernel: exact R12 (proven) versions.

#define BB 512
#define SS 1024
#define INF 64
#define HH 32
#define LL 4

typedef __fp16 v2h __attribute__((ext_vector_type(2)));

__device__ __forceinline__ v2h bch(unsigned u) { return __builtin_bit_cast(v2h, u); }
__device__ __forceinline__ unsigned bcu(v2h h) { return __builtin_bit_cast(unsigned, h); }

template <int CTRL>
__device__ __forceinline__ float dpp_add(float v) {
  int y = __builtin_amdgcn_update_dpp(0, __float_as_int(v), CTRL, 0xF, 0xF, true);
  return v + __int_as_float(y);
}
template <int CTRL>
__device__ __forceinline__ float dpp_mov(float v) {
  int y = __builtin_amdgcn_update_dpp(0, __float_as_int(v), CTRL, 0xF, 0xF, true);
  return __int_as_float(y);
}

// tanh(a) = 1 - 2/(e^{2a}+1); e^{2a} = 2^(a * 2/ln2). v_exp + v_rcp + fma.
__device__ __forceinline__ float tanh_fast(float a) {
  const float e = __builtin_amdgcn_exp2f(a * 2.885390081777927f);
  const float r = __builtin_amdgcn_rcpf(e + 1.0f);
  return __builtin_fmaf(-2.0f, r, 1.0f);
}

// 16-half dot (ks-half): 8 fdot2 in 2 chains of depth 4.
__device__ __forceinline__ float dot16p(const v2h* w, const v2h* v) {
  float a = 0.f, c = 0.f;
#pragma unroll
  for (int j = 0; j < 4; ++j) {
    a = __builtin_amdgcn_fdot2(w[2 * j + 0], v[2 * j + 0], a, false);
    c = __builtin_amdgcn_fdot2(w[2 * j + 1], v[2 * j + 1], c, false);
  }
  return a + c;
}

// lgkmcnt-only barrier: drains LDS ops (cross-wave handoff) but leaves global
// loads/stores in flight (u0 prefetch, hfin/logit stores).
#define BAR() asm volatile("s_waitcnt lgkmcnt(0)\n\ts_barrier" ::: "memory")

// ---------------- u0 = x @ W_ih0^T + (b_ih0 + b_hh0) ----------------
// Proven R8-R12 version: W (8KB) + bias staged in LDS; thread-per-row GEMV.
__global__ __launch_bounds__(256) void u0_kernel(
    const float* __restrict__ x, const float* __restrict__ W_ih0,
    const float* __restrict__ b_ih, const float* __restrict__ b_hh,
    float* __restrict__ u0) {
  __shared__ float Wl[HH * INF];  // [u][k]
  __shared__ float bl[HH];
  const int tid = threadIdx.x;
  {
    const float4* src = (const float4*)W_ih0;
    float4* dst = (float4*)Wl;
    dst[tid] = src[tid];
    dst[tid + 256] = src[tid + 256];
    if (tid < HH) bl[tid] = b_ih[tid] + b_hh[tid];
  }
  __syncthreads();

  const int row = blockIdx.x * 256 + tid;  // 2048 blocks x 256 rows
  const float4* xr = (const float4*)(x + (size_t)row * INF);
  float acc[HH];
#pragma unroll
  for (int u = 0; u < HH; ++u) acc[u] = bl[u];
#pragma unroll 4
  for (int kc = 0; kc < 16; ++kc) {
    const float4 xv = xr[kc];
#pragma unroll
    for (int u = 0; u < HH; ++u) {
      const float4 wv = ((const float4*)Wl)[u * 16 + kc];  // wave-broadcast
      acc[u] += wv.x * xv.x + wv.y * xv.y + wv.z * xv.z + wv.w * xv.w;
    }
  }
  float4* op = (float4*)(u0 + (size_t)row * HH);
#pragma unroll
  for (int j = 0; j < 8; ++j)
    op[j] = make_float4(acc[4 * j], acc[4 * j + 1], acc[4 * j + 2], acc[4 * j + 3]);
}

// ---------------- recurrent kernel: 4 waves (one per layer), 8 ticks/barrier ----------------
__global__ __launch_bounds__(256, 2) void rnn_kernel(
    const float* __restrict__ u0g_all, const float* __restrict__ h_state,
    const float* __restrict__ W_ih_rest, const float* __restrict__ W_hh,
    const float* __restrict__ b_ih, const float* __restrict__ b_hh,
    const float* __restrict__ fc_w, const float* __restrict__ fc_b,
    float* __restrict__ out) {
  __shared__ int hb[LL][2][8][16];  // [layer][buf=n&1][i=tick-in-block][pair] f16x2
  __shared__ float h3f[2][8][32];   // [buf][i][unit]: wave3's f32 hv for FC
  __shared__ float lbuf[64];        // logit staging (wave 0)

  const int tid  = threadIdx.x;
  const int wid  = tid >> 6;   // wave id == layer id
  const int lane = tid & 63;
  const int b    = blockIdx.x; // one batch element per block
  const int ks   = lane & 1;   // k-split half
  const int h    = lane >> 1;  // output unit 0..31

  // weights: f16-packed h-matrices only (x-part of layer 0 lives in u0)
  v2h wih[8], whh[8];
  {
    const float2* ph = (const float2*)(W_hh + (size_t)(wid * HH + h) * HH + ks * 16);
#pragma unroll
    for (int j = 0; j < 8; ++j) whh[j] = __builtin_amdgcn_cvt_pkrtz(ph[j].x, ph[j].y);
  }
  float bias = 0.f;  // layer 0 bias folded into u0
  if (wid > 0) {
    const float2* pi =
        (const float2*)(W_ih_rest + (size_t)((wid - 1) * HH + h) * HH + ks * 16);
#pragma unroll
    for (int j = 0; j < 8; ++j) wih[j] = __builtin_amdgcn_cvt_pkrtz(pi[j].x, pi[j].y);
    bias = b_ih[wid * HH + h] + b_hh[wid * HH + h];
  }
  const float fcwh = fc_w[h] * 0.5f;  // both ks lanes hold hv -> 64-lane sum is 2x
  const float fcb  = fc_b[0];

  // own h(-1) straight into registers (packed ks-half)
  v2h sv[8];
  {
    const float2* hs = (const float2*)(h_state + (size_t)(wid * BB + b) * HH);
#pragma unroll
    for (int j = 0; j < 8; ++j)
      sv[j] = __builtin_amdgcn_cvt_pkrtz(hs[ks * 8 + j].x, hs[ks * 8 + j].y);
  }

  const float* ug = u0g_all + (size_t)b * SS * HH;
  float* const outrow = out + (size_t)b * SS;
  float* const hfin   = out + (size_t)BB * SS;

  auto ld8 = [&](const int* p, v2h* v) __attribute__((always_inline)) {
    const uint4* q = (const uint4*)p;
    uint4 A = q[0], B = q[1];
    v[0] = bch(A.x); v[1] = bch(A.y); v[2] = bch(A.z); v[3] = bch(A.w);
    v[4] = bch(B.x); v[5] = bch(B.y); v[6] = bch(B.z); v[7] = bch(B.w);
  };
  // pack own hv with neighbor-unit hv (quad_perm [2,3,2,3]); word m valid at lane 4m
  auto packpair = [&](float hv) __attribute__((always_inline)) {
    return bcu(__builtin_amdgcn_cvt_pkrtz(hv, dpp_mov<0xEE>(hv)));
  };
  auto store_pk = [&](int l, int buf, int slot, unsigned pk) __attribute__((always_inline)) {
    if ((lane & 3) == 0) hb[l][buf][slot][lane >> 2] = (int)pk;
  };
  auto fcred = [&](float v) __attribute__((always_inline)) {
    v = dpp_add<0x111>(v);  // row_shr:1
    v = dpp_add<0x112>(v);  // row_shr:2
    v = dpp_add<0x114>(v);  // row_shr:4
    v = dpp_add<0x118>(v);  // row_shr:8
    v = dpp_add<0x142>(v);  // row_bcast:15
    v = dpp_add<0x143>(v);  // row_bcast:31
    return v;               // lane 63 holds the 64-lane sum
  };

  // Schedule: wave l computes tick block T = 8(n-l)..8(n-l)+7 at iteration n
  // (active for l <= n <= 127+l). Writes go to hb[l][n&1][i]; the consumer
  // reads the producer's same-range block (written at n-1) from buf (n-1)&1.
  // Overwrite of hb[l][buf] at iter n is safe: its reader consumed it at n-1
  // and drained at BAR(n). FC (wave 0) processes wave3's block from n-1.
  // All waves execute exactly 132 barriers (n = 0..131).
  if (wid == 0) {
    float urA[8], urB[8];  // u0 prefetch, ping-pong by outer 2-unroll (rule #20)
#pragma unroll
    for (int i = 0; i < 8; ++i) urA[i] = ug[i * HH + h];  // block 0
    auto iter0 = [&](int n, int buf, float* urC, float* urN)
        __attribute__((always_inline)) {
      BAR();
      const bool fc_on = (n >= 4);   // n <= 131 by loop bound
      const bool cw    = (n <= 127);
      float a[8];
      if (fc_on) {
#pragma unroll
        for (int i = 0; i < 8; ++i) a[i] = h3f[buf ^ 1][i][h];
      }
      if (cw) {
        const int tb = 8 * (n + 1);  // prefetch u0 for next block (off-chain)
#pragma unroll
        for (int i = 0; i < 8; ++i) {
          int t = tb + i; t = t < SS ? t : SS - 1;
          urN[i] = ug[t * HH + h];   // survives BAR (lgkm-only)
        }
        float hv7 = 0.f;
#pragma unroll
        for (int i = 0; i < 8; ++i) {
          float acc = dot16p(whh, sv);
          acc = dpp_add<0xB1>(acc) + urC[i];  // u0 holds x-part + full bias0
          const float hv = tanh_fast(acc);
          const unsigned pk = packpair(hv);
          store_pk(0, buf, i, pk);
          ld8(&hb[0][buf][i][ks * 8], sv);    // own carry (in-order DS RAW)
          if (i == 7) hv7 = hv;
        }
        if (n == 127 && ks == 0) hfin[(0 * BB + b) * HH + h] = hv7;
      }
      if (fc_on) {  // FC for wave3's block from iter n-1: t = 8(n-4)+i
        const int tf0 = 8 * (n - 4);
#pragma unroll
        for (int i = 0; i < 8; ++i) {
          float v = fcred(a[i] * fcwh);
          if (lane == 63) lbuf[(tf0 + i) & 63] = v + fcb;
        }
        if (((n - 4) & 7) == 7) {  // coalesced flush of 64 logits
          float lv = lbuf[lane];
          outrow[(tf0 + 7) - 63 + lane] = lv;
        }
      }
    };
    for (int n0 = 0; n0 < 132; n0 += 2) {
      iter0(n0, 0, urA, urB);
      iter0(n0 + 1, 1, urB, urA);
    }
  } else {
    v2h vi[8][8];  // producer block, read up-front each iteration
    auto iterl = [&](int n, int buf) __attribute__((always_inline)) {
      BAR();
      const bool cw = (n >= wid && n <= 127 + wid);
      if (cw) {
#pragma unroll
        for (int i = 0; i < 8; ++i)
          ld8(&hb[wid - 1][buf ^ 1][i][ks * 8], vi[i]);  // in-order; tick i waits
        float hv7 = 0.f;
#pragma unroll
        for (int i = 0; i < 8; ++i) {
          float acc = dot16p(wih, vi[i]) + dot16p(whh, sv);
          acc = dpp_add<0xB1>(acc) + bias;
          const float hv = tanh_fast(acc);
          const unsigned pk = packpair(hv);
          store_pk(wid, buf, i, pk);
          if (wid == 3 && ks == 0) h3f[buf][i][h] = hv;  // f32 handoff to FC
          ld8(&hb[wid][buf][i][ks * 8], sv);             // own carry
          if (i == 7) hv7 = hv;
        }
        if (n == 127 + wid && ks == 0) hfin[(wid * BB + b) * HH + h] = hv7;
      }
    };
    for (int n0 = 0; n0 < 132; n0 += 2) {
      iterl(n0, 0);
      iterl(n0 + 1, 1);
    }
  }
}

__global__ __launch_bounds__(256) void softmax_kernel(float* __restrict__ out) {
  __shared__ float red[8];
  const int row = blockIdx.x;
  float* p = out + (size_t)row * SS;
  const int tid = threadIdx.x;
  float4 v = ((const float4*)p)[tid];  // 256 threads x 4 = 1024 logits
  float m = fmaxf(fmaxf(v.x, v.y), fmaxf(v.z, v.w));
#pragma unroll
  for (int d = 32; d >= 1; d >>= 1) m = fmaxf(m, __shfl_xor(m, d));
  if ((tid & 63) == 0) red[tid >> 6] = m;
  __syncthreads();
  m = fmaxf(fmaxf(red[0], red[1]), fmaxf(red[2], red[3]));
  const float e0 = __expf(v.x - m), e1 = __expf(v.y - m);
  const float e2 = __expf(v.z - m), e3 = __expf(v.w - m);
  float s = (e0 + e1) + (e2 + e3);
#pragma unroll
  for (int d = 32; d >= 1; d >>= 1) s += __shfl_xor(s, d);
  if ((tid & 63) == 0) red[4 + (tid >> 6)] = s;
  __syncthreads();
  s = (red[4] + red[5]) + (red[6] + red[7]);
  const float inv = 1.0f / s;
  float4 o;
  o.x = e0 * inv; o.y = e1 * inv; o.z = e2 * inv; o.w = e3 * inv;
  ((float4*)p)[tid] = o;
}

extern "C" void kernel_launch(void* const* d_in, const int* in_sizes, int n_in,
                              void* d_out, int out_size, void* d_ws, size_t ws_size,
                              hipStream_t stream) {
  const float* x         = (const float*)d_in[0];
  const float* h_state   = (const float*)d_in[1];
  const float* W_ih0     = (const float*)d_in[2];
  const float* W_ih_rest = (const float*)d_in[3];
  const float* W_hh      = (const float*)d_in[4];
  const float* b_ih      = (const float*)d_in[5];
  const float* b_hh      = (const float*)d_in[6];
  const float* fc_w      = (const float*)d_in[7];
  const float* fc_b      = (const float*)d_in[8];
  float* out = (float*)d_out;
  float* u0  = (float*)d_ws;  // [B,S,32] fp32 = 67 MB scratch

  hipLaunchKernelGGL(u0_kernel, dim3((BB * SS) / 256), dim3(256), 0, stream,
                     x, W_ih0, b_ih, b_hh, u0);
  hipLaunchKernelGGL(rnn_kernel, dim3(BB), dim3(256), 0, stream,
                     u0, h_state, W_ih_rest, W_hh, b_ih, b_hh, fc_w, fc_b, out);
  hipLaunchKernelGGL(softmax_kernel, dim3(BB), dim3(256), 0, stream, out);
}

// Round 8
// 427.523 us; speedup vs baseline: 1.4640x; 1.0279x over previous
//
#include <hip/hip_runtime.h>

// RadarRnn1: 4-layer tanh RNN (B=512,S=1024,IN=64,H=32) + per-step FC + softmax over S.
// R16: R15 (k=8) measured 4146cy/iter = 518cy/tick vs ~290cy serial chain; the
// barrier fixed-cost is partially amortized, rest is issue/DS crowding. Three
// low-risk changes, arithmetic bit-identical:
//  - k=16 ticks/barrier (68 iters): remaining fixed-cost amortization. Input
//    blocks read 4-ticks-at-a-time into two named register banks (viA/viB,
//    static indices under full unroll - rule #20) to bound VGPR.
//  - softmax fused into rnn epilogue: FC writes logits to a 4KB LDS row; after
//    the final barrier all 4 waves run the exact softmax sequence (identical
//    256-thread float4 pattern + reduction order => bit-identical) and write
//    probs once. Removes a launch + 2MB global write + 2MB read.
//  - u0_kernel unchanged (proven).

#define BB 512
#define SS 1024
#define INF 64
#define HH 32
#define LL 4
#define KB 16  // ticks per barrier iteration

typedef __fp16 v2h __attribute__((ext_vector_type(2)));

__device__ __forceinline__ v2h bch(unsigned u) { return __builtin_bit_cast(v2h, u); }
__device__ __forceinline__ unsigned bcu(v2h h) { return __builtin_bit_cast(unsigned, h); }

template <int CTRL>
__device__ __forceinline__ float dpp_add(float v) {
  int y = __builtin_amdgcn_update_dpp(0, __float_as_int(v), CTRL, 0xF, 0xF, true);
  return v + __int_as_float(y);
}
template <int CTRL>
__device__ __forceinline__ float dpp_mov(float v) {
  int y = __builtin_amdgcn_update_dpp(0, __float_as_int(v), CTRL, 0xF, 0xF, true);
  return __int_as_float(y);
}

// tanh(a) = 1 - 2/(e^{2a}+1); e^{2a} = 2^(a * 2/ln2). v_exp + v_rcp + fma.
__device__ __forceinline__ float tanh_fast(float a) {
  const float e = __builtin_amdgcn_exp2f(a * 2.885390081777927f);
  const float r = __builtin_amdgcn_rcpf(e + 1.0f);
  return __builtin_fmaf(-2.0f, r, 1.0f);
}

// 16-half dot (ks-half): 8 fdot2 in 2 chains of depth 4.
__device__ __forceinline__ float dot16p(const v2h* w, const v2h* v) {
  float a = 0.f, c = 0.f;
#pragma unroll
  for (int j = 0; j < 4; ++j) {
    a = __builtin_amdgcn_fdot2(w[2 * j + 0], v[2 * j + 0], a, false);
    c = __builtin_amdgcn_fdot2(w[2 * j + 1], v[2 * j + 1], c, false);
  }
  return a + c;
}

// lgkmcnt-only barrier: drains LDS ops (cross-wave handoff) but leaves global
// loads/stores in flight (u0 prefetch, hfin stores).
#define BAR() asm volatile("s_waitcnt lgkmcnt(0)\n\ts_barrier" ::: "memory")

// ---------------- u0 = x @ W_ih0^T + (b_ih0 + b_hh0) ----------------
// Proven R8-R15 version: W (8KB) + bias staged in LDS; thread-per-row GEMV.
__global__ __launch_bounds__(256) void u0_kernel(
    const float* __restrict__ x, const float* __restrict__ W_ih0,
    const float* __restrict__ b_ih, const float* __restrict__ b_hh,
    float* __restrict__ u0) {
  __shared__ float Wl[HH * INF];  // [u][k]
  __shared__ float bl[HH];
  const int tid = threadIdx.x;
  {
    const float4* src = (const float4*)W_ih0;
    float4* dst = (float4*)Wl;
    dst[tid] = src[tid];
    dst[tid + 256] = src[tid + 256];
    if (tid < HH) bl[tid] = b_ih[tid] + b_hh[tid];
  }
  __syncthreads();

  const int row = blockIdx.x * 256 + tid;  // 2048 blocks x 256 rows
  const float4* xr = (const float4*)(x + (size_t)row * INF);
  float acc[HH];
#pragma unroll
  for (int u = 0; u < HH; ++u) acc[u] = bl[u];
#pragma unroll 4
  for (int kc = 0; kc < 16; ++kc) {
    const float4 xv = xr[kc];
#pragma unroll
    for (int u = 0; u < HH; ++u) {
      const float4 wv = ((const float4*)Wl)[u * 16 + kc];  // wave-broadcast
      acc[u] += wv.x * xv.x + wv.y * xv.y + wv.z * xv.z + wv.w * xv.w;
    }
  }
  float4* op = (float4*)(u0 + (size_t)row * HH);
#pragma unroll
  for (int j = 0; j < 8; ++j)
    op[j] = make_float4(acc[4 * j], acc[4 * j + 1], acc[4 * j + 2], acc[4 * j + 3]);
}

// ---------------- recurrent kernel: 4 waves (one per layer), 16 ticks/barrier,
// fused per-row softmax epilogue ----------------
__global__ __launch_bounds__(256, 2) void rnn_kernel(
    const float* __restrict__ u0g_all, const float* __restrict__ h_state,
    const float* __restrict__ W_ih_rest, const float* __restrict__ W_hh,
    const float* __restrict__ b_ih, const float* __restrict__ b_hh,
    const float* __restrict__ fc_w, const float* __restrict__ fc_b,
    float* __restrict__ out) {
  __shared__ int hb[LL][2][KB][16];  // [layer][buf=n&1][i=tick-in-block][pair] f16x2
  __shared__ float h3f[2][KB][32];   // [buf][i][unit]: wave3's f32 hv for FC
  __shared__ float lrow[SS];         // full logit row (4KB), softmaxed at the end
  __shared__ float red[8];           // softmax cross-wave reduce

  const int tid  = threadIdx.x;
  const int wid  = tid >> 6;   // wave id == layer id
  const int lane = tid & 63;
  const int b    = blockIdx.x; // one batch element per block
  const int ks   = lane & 1;   // k-split half
  const int h    = lane >> 1;  // output unit 0..31

  // weights: f16-packed h-matrices only (x-part of layer 0 lives in u0)
  v2h wih[8], whh[8];
  {
    const float2* ph = (const float2*)(W_hh + (size_t)(wid * HH + h) * HH + ks * 16);
#pragma unroll
    for (int j = 0; j < 8; ++j) whh[j] = __builtin_amdgcn_cvt_pkrtz(ph[j].x, ph[j].y);
  }
  float bias = 0.f;  // layer 0 bias folded into u0
  if (wid > 0) {
    const float2* pi =
        (const float2*)(W_ih_rest + (size_t)((wid - 1) * HH + h) * HH + ks * 16);
#pragma unroll
    for (int j = 0; j < 8; ++j) wih[j] = __builtin_amdgcn_cvt_pkrtz(pi[j].x, pi[j].y);
    bias = b_ih[wid * HH + h] + b_hh[wid * HH + h];
  }
  const float fcwh = fc_w[h] * 0.5f;  // both ks lanes hold hv -> 64-lane sum is 2x
  const float fcb  = fc_b[0];

  // own h(-1) straight into registers (packed ks-half)
  v2h sv[8];
  {
    const float2* hs = (const float2*)(h_state + (size_t)(wid * BB + b) * HH);
#pragma unroll
    for (int j = 0; j < 8; ++j)
      sv[j] = __builtin_amdgcn_cvt_pkrtz(hs[ks * 8 + j].x, hs[ks * 8 + j].y);
  }

  const float* ug = u0g_all + (size_t)b * SS * HH;
  float* const hfin = out + (size_t)BB * SS;

  auto ld8 = [&](const int* p, v2h* v) __attribute__((always_inline)) {
    const uint4* q = (const uint4*)p;
    uint4 A = q[0], B = q[1];
    v[0] = bch(A.x); v[1] = bch(A.y); v[2] = bch(A.z); v[3] = bch(A.w);
    v[4] = bch(B.x); v[5] = bch(B.y); v[6] = bch(B.z); v[7] = bch(B.w);
  };
  // pack own hv with neighbor-unit hv (quad_perm [2,3,2,3]); word m valid at lane 4m
  auto packpair = [&](float hv) __attribute__((always_inline)) {
    return bcu(__builtin_amdgcn_cvt_pkrtz(hv, dpp_mov<0xEE>(hv)));
  };
  auto store_pk = [&](int l, int buf, int slot, unsigned pk) __attribute__((always_inline)) {
    if ((lane & 3) == 0) hb[l][buf][slot][lane >> 2] = (int)pk;
  };
  auto fcred = [&](float v) __attribute__((always_inline)) {
    v = dpp_add<0x111>(v);  // row_shr:1
    v = dpp_add<0x112>(v);  // row_shr:2
    v = dpp_add<0x114>(v);  // row_shr:4
    v = dpp_add<0x118>(v);  // row_shr:8
    v = dpp_add<0x142>(v);  // row_bcast:15
    v = dpp_add<0x143>(v);  // row_bcast:31
    return v;               // lane 63 holds the 64-lane sum
  };

  // Schedule: wave l computes tick block 16(n-l)..16(n-l)+15 at iteration n
  // (active for l <= n <= 63+l). Writes go to hb[l][n&1][i]; the consumer reads
  // the producer's same-range block (written at n-1) from buf (n-1)&1. FC
  // (wave 0) processes wave3's block from n-1 into lrow. All waves execute
  // exactly 68 barriers (n = 0..67).
  if (wid == 0) {
    float urA[KB], urB[KB];  // u0 prefetch, ping-pong by outer 2-unroll
#pragma unroll
    for (int i = 0; i < KB; ++i) urA[i] = ug[i * HH + h];  // block 0
    auto iter0 = [&](int n, int buf, float* urC, float* urN)
        __attribute__((always_inline)) {
      BAR();
      const bool fc_on = (n >= 4);   // n <= 67 by loop bound
      const bool cw    = (n <= 63);
      float a[KB];
      if (fc_on) {
#pragma unroll
        for (int i = 0; i < KB; ++i) a[i] = h3f[buf ^ 1][i][h];
      }
      if (cw) {
        const int tb = KB * (n + 1);  // prefetch u0 for next block (off-chain)
#pragma unroll
        for (int i = 0; i < KB; ++i) {
          int t = tb + i; t = t < SS ? t : SS - 1;
          urN[i] = ug[t * HH + h];    // survives BAR (lgkm-only)
        }
        float hvL = 0.f;
#pragma unroll
        for (int i = 0; i < KB; ++i) {
          float acc = dot16p(whh, sv);
          acc = dpp_add<0xB1>(acc) + urC[i];  // u0 holds x-part + full bias0
          const float hv = tanh_fast(acc);
          const unsigned pk = packpair(hv);
          store_pk(0, buf, i, pk);
          ld8(&hb[0][buf][i][ks * 8], sv);    // own carry (in-order DS RAW)
          if (i == KB - 1) hvL = hv;
        }
        if (n == 63 && ks == 0) hfin[(0 * BB + b) * HH + h] = hvL;
      }
      if (fc_on) {  // FC for wave3's block from iter n-1: t = 16(n-4)+i
        const int tf0 = KB * (n - 4);
#pragma unroll
        for (int i = 0; i < KB; ++i) {
          float v = fcred(a[i] * fcwh);
          if (lane == 63) lrow[tf0 + i] = v + fcb;
        }
      }
    };
    for (int n0 = 0; n0 < 68; n0 += 2) {
      iter0(n0, 0, urA, urB);
      iter0(n0 + 1, 1, urB, urA);
    }
  } else {
    v2h viA[4][8], viB[4][8];  // input groups of 4 ticks, double-banked
    auto ldgrp = [&](int buf, int g, v2h (*vv)[8]) __attribute__((always_inline)) {
#pragma unroll
      for (int q = 0; q < 4; ++q)
        ld8(&hb[wid - 1][buf ^ 1][g * 4 + q][ks * 8], vv[q]);
    };
    auto dogrp = [&](int n, int buf, int g, v2h (*vc)[8], float& hvL)
        __attribute__((always_inline)) {
#pragma unroll
      for (int q = 0; q < 4; ++q) {
        const int i = g * 4 + q;
        float accA = dot16p(wih, vc[q]);      // independent: overlaps carry wait
        float acc = accA + dot16p(whh, sv);
        acc = dpp_add<0xB1>(acc) + bias;
        const float hv = tanh_fast(acc);
        const unsigned pk = packpair(hv);
        store_pk(wid, buf, i, pk);
        if (wid == 3 && ks == 0) h3f[buf][i][h] = hv;  // f32 handoff to FC
        ld8(&hb[wid][buf][i][ks * 8], sv);             // own carry
        if (i == KB - 1) hvL = hv;
      }
    };
    auto iterl = [&](int n, int buf) __attribute__((always_inline)) {
      BAR();
      const bool cw = (n >= wid && n <= 63 + wid);
      if (cw) {
        float hvL = 0.f;
        ldgrp(buf, 0, viA);
        ldgrp(buf, 1, viB);          // prefetch group 1
        dogrp(n, buf, 0, viA, hvL);
        ldgrp(buf, 2, viA);          // prefetch group 2 (viA free)
        dogrp(n, buf, 1, viB, hvL);
        ldgrp(buf, 3, viB);          // prefetch group 3 (viB free)
        dogrp(n, buf, 2, viA, hvL);
        dogrp(n, buf, 3, viB, hvL);
        if (n == 63 + wid && ks == 0) hfin[(wid * BB + b) * HH + h] = hvL;
      }
    };
    for (int n0 = 0; n0 < 68; n0 += 2) {
      iterl(n0, 0);
      iterl(n0 + 1, 1);
    }
  }

  // ---- fused softmax over lrow (exact replica of the old softmax_kernel) ----
  __syncthreads();  // all lrow writes (wave 0, LDS) visible to all waves
  {
    float4 v = ((const float4*)lrow)[tid];  // 256 threads x 4 = 1024 logits
    float m = fmaxf(fmaxf(v.x, v.y), fmaxf(v.z, v.w));
#pragma unroll
    for (int d = 32; d >= 1; d >>= 1) m = fmaxf(m, __shfl_xor(m, d));
    if ((tid & 63) == 0) red[tid >> 6] = m;
    __syncthreads();
    m = fmaxf(fmaxf(red[0], red[1]), fmaxf(red[2], red[3]));
    const float e0 = __expf(v.x - m), e1 = __expf(v.y - m);
    const float e2 = __expf(v.z - m), e3 = __expf(v.w - m);
    float s = (e0 + e1) + (e2 + e3);
#pragma unroll
    for (int d = 32; d >= 1; d >>= 1) s += __shfl_xor(s, d);
    if ((tid & 63) == 0) red[4 + (tid >> 6)] = s;
    __syncthreads();
    s = (red[4] + red[5]) + (red[6] + red[7]);
    const float inv = 1.0f / s;
    float4 o;
    o.x = e0 * inv; o.y = e1 * inv; o.z = e2 * inv; o.w = e3 * inv;
    ((float4*)(out + (size_t)b * SS))[tid] = o;
  }
}

extern "C" void kernel_launch(void* const* d_in, const int* in_sizes, int n_in,
                              void* d_out, int out_size, void* d_ws, size_t ws_size,
                              hipStream_t stream) {
  const float* x         = (const float*)d_in[0];
  const float* h_state   = (const float*)d_in[1];
  const float* W_ih0     = (const float*)d_in[2];
  const float* W_ih_rest = (const float*)d_in[3];
  const float* W_hh      = (const float*)d_in[4];
  const float* b_ih      = (const float*)d_in[5];
  const float* b_hh      = (const float*)d_in[6];
  const float* fc_w      = (const float*)d_in[7];
  const float* fc_b      = (const float*)d_in[8];
  float* out = (float*)d_out;
  float* u0  = (float*)d_ws;  // [B,S,32] fp32 = 67 MB scratch

  hipLaunchKernelGGL(u0_kernel, dim3((BB * SS) / 256), dim3(256), 0, stream,
                     x, W_ih0, b_ih, b_hh, u0);
  hipLaunchKernelGGL(rnn_kernel, dim3(BB), dim3(256), 0, stream,
                     u0, h_state, W_ih_rest, W_hh, b_ih, b_hh, fc_w, fc_b, out);
}